// Round 14
// baseline (1205.549 us; speedup 1.0000x reference)
//
#include <hip/hip_runtime.h>

// RNN: h_t = tanh(x[b,t]*W_ih + b_ih + b_hh + h_{t-1} @ W_hh^T), out = h_T @ W_out^T + b_out
// B=256 T=2048 H=256 P=24, fp32 in/out. One WG/batch (256 WGs = 256 CUs), 256 thr, 4 waves.
//
// Round-23: MFMA. R13 verdict: pk_fma_f16 = pk_fma_f32 rate -> ALL vector
// paths cap at 512 cyc/SIMD/step. The matrix pipe does the same matvec in
// 32 mfma_f32_16x16x32_f16 per wave (~160 cyc issue), absorbs the K-reduce
// (butterfly + pair-adds deleted), accumulates in f32 (precision ~R12).
// Layout (1 wave/SIMD, wave w owns y[64w..64w+63] as 4 col-blocks):
//  - A operand = h broadcast: lane l reads h[32kb + 8*(l>>4) + j] -- one
//    ds_read_b128 per kb at base+(l>>4)*16+kb*64 (16-lane same-addr
//    broadcast groups, conflict-free). Rows of A replicated -> D rows
//    replicated.
//  - B operand = W_hh in regs: lane holds W[64w+16rb+(l&15)][same k-slot
//    formula]. A and B use the SAME (l>>4,j)->k map, so any hardware
//    k-permutation cancels (sum over k is permutation-invariant) -- only
//    the m89-verified C/D map (col = lane&15) matters. D[.,n] = y[N0+n].
//  - acc[rb].x is the full row sum: tail = 4 tanh + 4 ds_write_b16 on
//    lanes 0-15 only (no butterfly, no dup writes).
//  - 8 ds_read_b128 + 32 MFMA (4 chains interleaved, dep distance 4) +
//    tail + lgkm-only barrier per step. VGPR ~200 (128 W + 32 af + 16 acc
//    + misc) < 256 cap at (256,1) -- R11's spill was at ~320 demand.
// Locked-in: fp16 h storage (absmax budget proven R12/R13); lgkm-only
// barrier; x block-prefetch one 8-step block ahead; fp32 tanh tail
// (exp2/rcp); fp32 head on tid<24.

#define BB 256
#define TT 2048
#define HH 256
#define PP 24

typedef _Float16 half_t;
typedef _Float16 h8v __attribute__((ext_vector_type(8)));
typedef float    f4v __attribute__((ext_vector_type(4)));

__device__ __forceinline__ f4v mfma16(h8v a, h8v b, f4v c) {
    return __builtin_amdgcn_mfma_f32_16x16x32_f16(a, b, c, 0, 0, 0);
}

// LDS-only barrier: orders the ds_writes without draining vmcnt (x prefetch
// stays in flight; compiler waits vmcnt at first use).
__device__ __forceinline__ void lds_barrier() {
    asm volatile("s_waitcnt lgkmcnt(0)\n\ts_barrier" ::: "memory");
}

__global__ __launch_bounds__(256, 1)
void rnn_persist(const float* __restrict__ x,
                 const float* __restrict__ W_ih,
                 const float* __restrict__ W_hh,
                 const float* __restrict__ b_ih,
                 const float* __restrict__ b_hh,
                 const float* __restrict__ W_out,
                 const float* __restrict__ b_out,
                 float* __restrict__ out)
{
    __shared__ __align__(16) half_t hbuf[2][HH];   // 2 x 512 B, no pad needed

    const int tid  = threadIdx.x;
    const int b    = blockIdx.x;
    const int w    = tid >> 6;        // wave 0..3 -> owns y[64w .. 64w+63]
    const int l    = tid & 63;
    const int ln   = l & 15;          // col within 16-block (C/D col = lane&15)
    const int kg   = l >> 4;          // k-group 0..3 (8 k-slots each)

    hbuf[0][tid] = (half_t)0.f;       // h_0 = 0 (256 threads cover 256 rows)

    // B-operand weights in regs: wf[rb][kb] = W[64w+16rb+ln][32kb+8kg+j],
    // j=0..7 (f16). Same (kg,j)->k formula as the A-side h reads -> any HW
    // k-permutation cancels. 4*8*4 = 128 VGPRs.
    h8v wf[4][8];
    #pragma unroll
    for (int rb = 0; rb < 4; ++rb) {
        #pragma unroll
        for (int kb = 0; kb < 8; ++kb) {
            const float* p = W_hh + (size_t)(64 * w + 16 * rb + ln) * HH
                                   + 32 * kb + 8 * kg;
            const float4 qa = *(const float4*)p;
            const float4 qb = *(const float4*)(p + 4);
            wf[rb][kb] = (h8v){(half_t)qa.x, (half_t)qa.y, (half_t)qa.z,
                               (half_t)qa.w, (half_t)qb.x, (half_t)qb.y,
                               (half_t)qb.z, (half_t)qb.w};
        }
    }

    // Rows this lane finalizes (lanes 0-15 only): 64w + 16rb + ln.
    float wihv[4], cbv[4];
    #pragma unroll
    for (int rb = 0; rb < 4; ++rb) {
        const int o = 64 * w + 16 * rb + ln;
        wihv[rb] = W_ih[o];
        cbv[rb]  = b_ih[o] + b_hh[o];
    }
    const bool writer = (l < 16);

    __syncthreads();

    const float* xb = x + b * TT;

    auto step = [&](const half_t* __restrict__ cur, half_t* __restrict__ nxt,
                    float xt) __attribute__((always_inline)) {
        // A fragments: 8 broadcast ds_read_b128 (base + kg*16 + kb*64 bytes).
        const h8v* hp = (const h8v*)(cur + 8 * kg);
        h8v af[8];
        #pragma unroll
        for (int kb = 0; kb < 8; ++kb) af[kb] = hp[4 * kb];

        // 4 interleaved 8-deep MFMA chains (dep distance 4 insts).
        f4v a0 = {0.f, 0.f, 0.f, 0.f}, a1 = a0, a2 = a0, a3 = a0;
        #pragma unroll
        for (int kb = 0; kb < 8; ++kb) {
            a0 = mfma16(af[kb], wf[0][kb], a0);
            a1 = mfma16(af[kb], wf[1][kb], a1);
            a2 = mfma16(af[kb], wf[2][kb], a2);
            a3 = mfma16(af[kb], wf[3][kb], a3);
        }

        // Tail: D col ln holds y[64w+16rb+ln] (rows replicated; .x static).
        if (writer) {
            const float y0 = a0.x, y1 = a1.x, y2 = a2.x, y3 = a3.x;
            const float u0 = fmaf(xt, wihv[0], cbv[0]) + y0;
            const float u1 = fmaf(xt, wihv[1], cbv[1]) + y1;
            const float u2 = fmaf(xt, wihv[2], cbv[2]) + y2;
            const float u3 = fmaf(xt, wihv[3], cbv[3]) + y3;
            const float p0 = __builtin_amdgcn_exp2f(u0 * 2.8853900817779268f);
            const float p1 = __builtin_amdgcn_exp2f(u1 * 2.8853900817779268f);
            const float p2 = __builtin_amdgcn_exp2f(u2 * 2.8853900817779268f);
            const float p3 = __builtin_amdgcn_exp2f(u3 * 2.8853900817779268f);
            const float t0 = fmaf(-2.f, __builtin_amdgcn_rcpf(p0 + 1.f), 1.f);
            const float t1 = fmaf(-2.f, __builtin_amdgcn_rcpf(p1 + 1.f), 1.f);
            const float t2 = fmaf(-2.f, __builtin_amdgcn_rcpf(p2 + 1.f), 1.f);
            const float t3 = fmaf(-2.f, __builtin_amdgcn_rcpf(p3 + 1.f), 1.f);
            nxt[64 * w +  0 + ln] = (half_t)t0;
            nxt[64 * w + 16 + ln] = (half_t)t1;
            nxt[64 * w + 32 + ln] = (half_t)t2;
            nxt[64 * w + 48 + ln] = (half_t)t3;
        }
        lds_barrier();   // lgkm-only: x prefetch stays in flight
    };

    // x block-prefetch: block's two float4s fetched one 8-step block ahead.
    float4 xa = *(const float4*)(xb + 0);
    float4 xc = *(const float4*)(xb + 4);
    for (int t = 0; t < TT; t += 8) {
        const int tn = (t + 8 < TT) ? (t + 8) : t;   // clamped (last block refetch)
        const float4 xa_n = *(const float4*)(xb + tn);
        const float4 xc_n = *(const float4*)(xb + tn + 4);
        step(hbuf[0], hbuf[1], xa.x);
        step(hbuf[1], hbuf[0], xa.y);
        step(hbuf[0], hbuf[1], xa.z);
        step(hbuf[1], hbuf[0], xa.w);
        step(hbuf[0], hbuf[1], xc.x);
        step(hbuf[1], hbuf[0], xc.y);
        step(hbuf[0], hbuf[1], xc.z);
        step(hbuf[1], hbuf[0], xc.w);
        xa = xa_n;
        xc = xc_n;
    }

    // Head: h_T in hbuf[0] (TT % 8 == 0). out[b,p] = b_out[p] + W_out[p,:].h_T
    if (tid < PP) {
        const float* wo = W_out + tid * HH;
        float s0 = 0.f, s1 = 0.f, s2 = 0.f, s3 = 0.f;
        #pragma unroll
        for (int h = 0; h < HH; h += 4) {
            s0 = fmaf(wo[h + 0], (float)hbuf[0][h + 0], s0);
            s1 = fmaf(wo[h + 1], (float)hbuf[0][h + 1], s1);
            s2 = fmaf(wo[h + 2], (float)hbuf[0][h + 2], s2);
            s3 = fmaf(wo[h + 3], (float)hbuf[0][h + 3], s3);
        }
        out[b * PP + tid] = b_out[tid] + (s0 + s1) + (s2 + s3);
    }
}

extern "C" void kernel_launch(void* const* d_in, const int* in_sizes, int n_in,
                              void* d_out, int out_size, void* d_ws, size_t ws_size,
                              hipStream_t stream) {
    const float* x     = (const float*)d_in[0];
    const float* W_ih  = (const float*)d_in[1];
    const float* W_hh  = (const float*)d_in[2];
    const float* b_ih  = (const float*)d_in[3];
    const float* b_hh  = (const float*)d_in[4];
    const float* W_out = (const float*)d_in[5];
    const float* b_out = (const float*)d_in[6];
    float* out = (float*)d_out;

    rnn_persist<<<BB, 256, 0, stream>>>(x, W_ih, W_hh, b_ih, b_hh, W_out, b_out, out);
}

// Round 15
// 868.344 us; speedup vs baseline: 1.3883x; 1.3883x over previous
//
#include <hip/hip_runtime.h>

// RNN: h_t = tanh(x[b,t]*W_ih + b_ih + b_hh + h_{t-1} @ W_hh^T), out = h_T @ W_out^T + b_out
// B=256 T=2048 H=256 P=24, fp32 in/out. One WG/batch (256 WGs = 256 CUs), 512 thr, 8 waves.
//
// Round-24: MFMA at 2 WAVES/SIMD. R14 (1 wave/SIMD) measured 16 cyc/MFMA
// (MfmaUtil 36.7% of a 1413-cyc step): the lone wave eats full MFMA dep
// latency + serial ds_read broadcast (~120cyc) + tanh tail + barrier, no
// overlap. The MFMA math floor is ~155 cyc/SIMD/step (32x4.85) -- 3.3x below
// the fp32 vector floor -- so keep the pipe, fix the schedule:
//  - 512 thr = 8 waves = 2/SIMD: two streams hide MFMA latency and each
//    other's read/tail/barrier phases. Wave w owns 32 rows (rb=0,1):
//    wf[2][8]=64 VGPRs, ~135 total -> no spill at 2 waves/EU.
//  - Per-wave split-K: 4 chains (rb x k-half, dep distance 4 insts) cover
//    ~20cyc latency even within one wave. Writer lanes combine
//    a_lo.x + a_hi.x (1 add/row); tail = 2 tanh + 2 ds_write_b16.
//  - Per SIMD per step: 32 MFMA (unchanged); per CU: 128.
// A/B layout (R14-verified, absmax 3.9e-3): A = h broadcast, lane l reads
// h[32kb+8*(l>>4)+j] (one ds_read_b128/kb, 16-lane same-addr broadcast);
// B = W_hh rows in regs, same (l>>4,j)->k formula -> HW k-permutation
// cancels; C/D col = lane&15, rows replicated -> acc.x is the row sum.
// Split-K reassociates -> absmax ~4e-3 class (threshold 2.36e-2).
// Locked-in: fp16 h storage; lgkm-only barrier (vmcnt stays in flight);
// x block-prefetch one 8-step block ahead; fp32 tanh (exp2/rcp); fp32 head.

#define BB 256
#define TT 2048
#define HH 256
#define PP 24

typedef _Float16 half_t;
typedef _Float16 h8v __attribute__((ext_vector_type(8)));
typedef float    f4v __attribute__((ext_vector_type(4)));

__device__ __forceinline__ f4v mfma16(h8v a, h8v b, f4v c) {
    return __builtin_amdgcn_mfma_f32_16x16x32_f16(a, b, c, 0, 0, 0);
}

// LDS-only barrier: orders the ds_writes without draining vmcnt (x prefetch
// stays in flight; compiler waits vmcnt at first use).
__device__ __forceinline__ void lds_barrier() {
    asm volatile("s_waitcnt lgkmcnt(0)\n\ts_barrier" ::: "memory");
}

__global__ __launch_bounds__(512, 2)
void rnn_persist(const float* __restrict__ x,
                 const float* __restrict__ W_ih,
                 const float* __restrict__ W_hh,
                 const float* __restrict__ b_ih,
                 const float* __restrict__ b_hh,
                 const float* __restrict__ W_out,
                 const float* __restrict__ b_out,
                 float* __restrict__ out)
{
    __shared__ __align__(16) half_t hbuf[2][HH];   // 2 x 512 B

    const int tid  = threadIdx.x;
    const int b    = blockIdx.x;
    const int w    = tid >> 6;        // wave 0..7 -> owns y[32w .. 32w+31]
    const int l    = tid & 63;
    const int ln   = l & 15;          // col within 16-block (C/D col = lane&15)
    const int kg   = l >> 4;          // k-group 0..3 (8 k-slots each)

    hbuf[0][tid & 255] = (half_t)0.f; // h_0 = 0 (2-dup same-addr, same value)

    // B-operand weights in regs: wf[rb][kb] = W[32w+16rb+ln][32kb+8kg+j],
    // j=0..7 (f16). 2*8*4 = 64 VGPRs.
    h8v wf[2][8];
    #pragma unroll
    for (int rb = 0; rb < 2; ++rb) {
        #pragma unroll
        for (int kb = 0; kb < 8; ++kb) {
            const float* p = W_hh + (size_t)(32 * w + 16 * rb + ln) * HH
                                   + 32 * kb + 8 * kg;
            const float4 qa = *(const float4*)p;
            const float4 qb = *(const float4*)(p + 4);
            wf[rb][kb] = (h8v){(half_t)qa.x, (half_t)qa.y, (half_t)qa.z,
                               (half_t)qa.w, (half_t)qb.x, (half_t)qb.y,
                               (half_t)qb.z, (half_t)qb.w};
        }
    }

    // Rows this lane finalizes (lanes 0-15 only): 32w + 16rb + ln.
    float wihv[2], cbv[2];
    #pragma unroll
    for (int rb = 0; rb < 2; ++rb) {
        const int o = 32 * w + 16 * rb + ln;
        wihv[rb] = W_ih[o];
        cbv[rb]  = b_ih[o] + b_hh[o];
    }
    const bool writer = (l < 16);

    __syncthreads();

    const float* xb = x + b * TT;

    auto step = [&](const half_t* __restrict__ cur, half_t* __restrict__ nxt,
                    float xt) __attribute__((always_inline)) {
        // A fragments: 8 broadcast ds_read_b128 (base + kg*16 + kb*64 bytes).
        const h8v* hp = (const h8v*)(cur + 8 * kg);
        h8v af[8];
        #pragma unroll
        for (int kb = 0; kb < 8; ++kb) af[kb] = hp[4 * kb];

        // 4 interleaved chains, dep distance 4: (rb0,lo)(rb1,lo)(rb0,hi)(rb1,hi).
        f4v a00 = {0.f, 0.f, 0.f, 0.f}, a10 = a00, a01 = a00, a11 = a00;
        #pragma unroll
        for (int kb = 0; kb < 4; ++kb) {
            a00 = mfma16(af[kb],     wf[0][kb],     a00);
            a10 = mfma16(af[kb],     wf[1][kb],     a10);
            a01 = mfma16(af[kb + 4], wf[0][kb + 4], a01);
            a11 = mfma16(af[kb + 4], wf[1][kb + 4], a11);
        }

        // Tail (writer lanes): split-K combine on .x (rows replicated).
        if (writer) {
            const float y0 = a00.x + a01.x;
            const float y1 = a10.x + a11.x;
            const float u0 = fmaf(xt, wihv[0], cbv[0]) + y0;
            const float u1 = fmaf(xt, wihv[1], cbv[1]) + y1;
            const float p0 = __builtin_amdgcn_exp2f(u0 * 2.8853900817779268f);
            const float p1 = __builtin_amdgcn_exp2f(u1 * 2.8853900817779268f);
            const float t0 = fmaf(-2.f, __builtin_amdgcn_rcpf(p0 + 1.f), 1.f);
            const float t1 = fmaf(-2.f, __builtin_amdgcn_rcpf(p1 + 1.f), 1.f);
            nxt[32 * w +  0 + ln] = (half_t)t0;
            nxt[32 * w + 16 + ln] = (half_t)t1;
        }
        lds_barrier();   // lgkm-only: x prefetch stays in flight
    };

    // x block-prefetch: block's two float4s fetched one 8-step block ahead.
    float4 xa = *(const float4*)(xb + 0);
    float4 xc = *(const float4*)(xb + 4);
    for (int t = 0; t < TT; t += 8) {
        const int tn = (t + 8 < TT) ? (t + 8) : t;   // clamped (last block refetch)
        const float4 xa_n = *(const float4*)(xb + tn);
        const float4 xc_n = *(const float4*)(xb + tn + 4);
        step(hbuf[0], hbuf[1], xa.x);
        step(hbuf[1], hbuf[0], xa.y);
        step(hbuf[0], hbuf[1], xa.z);
        step(hbuf[1], hbuf[0], xa.w);
        step(hbuf[0], hbuf[1], xc.x);
        step(hbuf[1], hbuf[0], xc.y);
        step(hbuf[0], hbuf[1], xc.z);
        step(hbuf[1], hbuf[0], xc.w);
        xa = xa_n;
        xc = xc_n;
    }

    // Head: h_T in hbuf[0] (TT % 8 == 0). out[b,p] = b_out[p] + W_out[p,:].h_T
    if (tid < PP) {
        const float* wo = W_out + tid * HH;
        float s0 = 0.f, s1 = 0.f, s2 = 0.f, s3 = 0.f;
        #pragma unroll
        for (int h = 0; h < HH; h += 4) {
            s0 = fmaf(wo[h + 0], (float)hbuf[0][h + 0], s0);
            s1 = fmaf(wo[h + 1], (float)hbuf[0][h + 1], s1);
            s2 = fmaf(wo[h + 2], (float)hbuf[0][h + 2], s2);
            s3 = fmaf(wo[h + 3], (float)hbuf[0][h + 3], s3);
        }
        out[b * PP + tid] = b_out[tid] + (s0 + s1) + (s2 + s3);
    }
}

extern "C" void kernel_launch(void* const* d_in, const int* in_sizes, int n_in,
                              void* d_out, int out_size, void* d_ws, size_t ws_size,
                              hipStream_t stream) {
    const float* x     = (const float*)d_in[0];
    const float* W_ih  = (const float*)d_in[1];
    const float* W_hh  = (const float*)d_in[2];
    const float* b_ih  = (const float*)d_in[3];
    const float* b_hh  = (const float*)d_in[4];
    const float* W_out = (const float*)d_in[5];
    const float* b_out = (const float*)d_in[6];
    float* out = (float*)d_out;

    rnn_persist<<<BB, 512, 0, stream>>>(x, W_ih, W_hh, b_ih, b_hh, W_out, b_out, out);
}